// Round 10
// baseline (107.592 us; speedup 1.0000x reference)
//
#include <hip/hip_runtime.h>
#include <math.h>

#ifndef M_PI
#define M_PI 3.14159265358979323846
#endif

#define T_LEN   262144
#define NBATCH  64
#define STEP    171
#define NSEG    1531          // (262144-512)/171 + 1
#define NPAIR   766           // ceil(1531/2); last pair has zero imag segment
#define WPB     128           // waves per batch -> 8192 waves total
#define HI_BIN  244           // exclusive upper band bin

typedef float    v2f __attribute__((ext_vector_type(2)));
typedef _Float16 v2h __attribute__((ext_vector_type(2)));   // one complex = 1 VGPR

__device__ __forceinline__ int bitrev3(int r) {
    return ((r & 1) << 2) | (r & 2) | ((r & 4) >> 2);
}

// ---- gfx950 cross-lane helpers (volatile pswap: R6-proven config) ----
__device__ __forceinline__ void pswap32h(v2h& a, v2h& b) {
    asm volatile("v_permlane32_swap_b32 %0, %1" : "+v"(a), "+v"(b));
}
__device__ __forceinline__ void pswap16h(v2h& a, v2h& b) {
    asm volatile("v_permlane16_swap_b32 %0, %1" : "+v"(a), "+v"(b));
}
template <int CTRL>
__device__ __forceinline__ v2h dpph(v2h x) {       // DPP on the packed complex
    int xi = __builtin_bit_cast(int, x);
    int r  = __builtin_amdgcn_mov_dpp(xi, CTRL, 0xF, 0xF, true);
    return __builtin_bit_cast(v2h, r);
}

// complex rotate in f16: z=(x,y), w=(c,s): d = (xc - ys, xs + yc). 2 full-rate VOP3P.
__device__ __forceinline__ v2h cmulh(v2h z, v2h w) {
    v2h t, d;
    asm("v_pk_mul_f16 %0, %1, %2 op_sel_hi:[1,0]"
        : "=v"(t) : "v"(z), "v"(w));
    asm("v_pk_fma_f16 %0, %1, %2, %3 op_sel:[1,1,0] op_sel_hi:[0,1,1] neg_lo:[1,0,0]"
        : "=v"(d) : "v"(z), "v"(w), "v"(t));
    return d;
}
// z * (-i) = (y, -x): single pk_mul with op_sel; m = (1, -1)
__device__ __forceinline__ v2h cmulNIh(v2h z, v2h m) {
    v2h d;
    asm("v_pk_mul_f16 %0, %1, %2 op_sel:[1,0] op_sel_hi:[0,1]"
        : "=v"(d) : "v"(z), "v"(m));
    return d;
}

// volatile pin: opaque def -> cannot be rematerialized or sunk into the loop
#define PINV(x) asm volatile("" : "+v"(x))

// ws layout: [0, 8192) per-wave partial band sums
__global__ __launch_bounds__(256, 4) void fft_band_k(const float* __restrict__ x,
                                                     float* __restrict__ ws) {
    // per-wave transpose scratch: 8 rows x 65 words (260 B) = 2080 B/wave
    __shared__ __align__(16) char ldsc[4 * 2080];

    const int L      = threadIdx.x & 63;
    const int wib    = threadIdx.x >> 6;
    const int waveId = (int)(blockIdx.x * 256 + threadIdx.x) >> 6;
    const int b      = waveId >> 7;           // / WPB
    const int winb   = waveId & (WPB - 1);

    char* wptr = ldsc + wib * 2080 + 4 * L;                            // + 260*q imm
    char* rptr = ldsc + wib * 2080 + 260 * (L & 7) + 4 * (L & 0x38);   // + 4*q imm

    // ---- per-wave loop-invariant constants (volatile-pinned vs remat) ----
    float wv[8];
#pragma unroll
    for (int r = 0; r < 8; ++r) {
        float n = (float)(L + 64 * r);
        wv[r] = 0.54f - 0.46f * __cosf((float)(2.0 * M_PI / 512.0) * n);
        PINV(wv[r]);
    }
    // weights at final (reg rho, lane L): k = L2 + 2*L4 + 4*L5 + 8*L0 + 16*L1 + 32*L3 + 64*bitrev3(rho)
    float wt[8];
#pragma unroll
    for (int p = 0; p < 8; ++p) {
        int k = ((L >> 2) & 1) + 2 * ((L >> 4) & 1) + 4 * ((L >> 5) & 1)
              + 8 * (L & 1) + 16 * ((L >> 1) & 1) + 32 * ((L >> 3) & 1)
              + 64 * bitrev3(p);
        int mb = (k <= 256) ? k : 512 - k;
        float wgt = 0.0f;
        if (mb >= 1 && mb < HI_BIN) {
            float f   = (float)mb * (3152.0f / 512.0f);
            float fsq = f * f;
            float num = 1.48693636e8f * fsq * fsq;
            float d1  = fsq + 424.36f;
            float d2  = fsq + 11599.29f;
            float d3  = fsq + 544496.41f;
            float d4  = fsq + 1.48693636e8f;
            float ratio = (num / (d1 * d4)) * rsqrtf(d2 * d3);
            wgt = ratio * ratio * 1.6141422e-9f;   // ratio^2 * 10^0.2 / (winpow*FS*nseg)
        }
        wt[p] = wgt;
        PINV(wt[p]);
    }
    // mid twiddles (c,s) = e^{-2pi i * bitrev3(r) * L / 512}, f16 (RNE via cast)
    v2h M[8];
#pragma unroll
    for (int r = 1; r < 8; ++r) {
        float ang = (float)(-2.0 * M_PI / 512.0) * (float)(bitrev3(r) * L);
        float s, c; __sincosf(ang, &s, &c);
        M[r] = (v2h){(_Float16)c, (_Float16)s};
        PINV(M[r]);
    }
    // cross-lane stage twiddles (m=32,16,8)
    float c32, s32, c16, s16;
    __sincosf((float)(-2.0 * M_PI) * (float)(L & 31) / 64.0f, &s32, &c32);
    __sincosf((float)(-2.0 * M_PI) * (float)(L & 15) / 32.0f, &s16, &c16);
    v2h W32 = (v2h){(_Float16)c32, (_Float16)s32};
    v2h W16 = (v2h){(_Float16)c16, (_Float16)s16};
    v2h W8, g8v;
    if (L & 8) { float s, c; __sincosf((float)(-2.0 * M_PI) * (float)(L & 7) / 16.0f, &s, &c);
                 W8 = (v2h){(_Float16)c, (_Float16)s}; g8v = (v2h){(_Float16)-1.f, (_Float16)-1.f}; }
    else       { W8 = (v2h){(_Float16)1.f, (_Float16)0.f}; g8v = (v2h){(_Float16)1.f, (_Float16)1.f}; }
    PINV(W32); PINV(W16); PINV(W8); PINV(g8v);

    const _Float16 C7 = (_Float16)0.70710678118654752f;
    v2h W81  = (v2h){C7, (_Float16)-0.70710678118654752f};
    v2h W83  = (v2h){(_Float16)-0.70710678118654752f, (_Float16)-0.70710678118654752f};
    v2h WNIm = (v2h){(_Float16)1.f, (_Float16)-1.f};      // for cmulNIh
    PINV(W81); PINV(W83); PINV(WNIm);

    // per-register f32 energy accumulators (weights folded in AFTER the loop)
    float accQ[8];
#pragma unroll
    for (int q = 0; q < 8; ++q) accQ[q] = 0.0f;

    const float* xb = x + (size_t)b * T_LEN;

    for (int p = winb; p < NPAIR; p += WPB) {
        const int s0 = 2 * p;
        v2h z[8];
        const float* p0 = xb + s0 * STEP + L;
        float a[8], bb[8];
#pragma unroll
        for (int r = 0; r < 8; ++r) a[r] = p0[64 * r];
        if (2 * p + 1 < NSEG) {               // wave-uniform; false only at p=765
#pragma unroll
            for (int r = 0; r < 8; ++r) bb[r] = p0[64 * r + STEP];
        } else {
#pragma unroll
            for (int r = 0; r < 8; ++r) bb[r] = 0.0f;
        }
        // f32 window multiply, then pack both segments into one f16 complex reg
#pragma unroll
        for (int r = 0; r < 8; ++r)
            z[r] = (v2h)__builtin_amdgcn_cvt_pkrtz(a[r] * wv[r], bb[r] * wv[r]);

        // ---- per-lane radix-2 DIF FFT-8 over registers (f16 packed complex) ----
        {
            v2h d0 = z[0] - z[4]; z[0] += z[4];
            v2h d1 = z[1] - z[5]; z[1] += z[5];
            v2h d2 = z[2] - z[6]; z[2] += z[6];
            v2h d3 = z[3] - z[7]; z[3] += z[7];
            z[4] = d0;
            z[5] = cmulh(d1, W81);
            z[6] = cmulNIh(d2, WNIm);
            z[7] = cmulh(d3, W83);
            v2h t;
            t = z[0] - z[2]; z[0] += z[2]; z[2] = t;
            t = z[1] - z[3]; z[1] += z[3]; z[3] = cmulNIh(t, WNIm);
            t = z[4] - z[6]; z[4] += z[6]; z[6] = t;
            t = z[5] - z[7]; z[5] += z[7]; z[7] = cmulNIh(t, WNIm);
#pragma unroll
            for (int g = 0; g < 8; g += 2) {
                t = z[g] - z[g + 1]; z[g] += z[g + 1]; z[g + 1] = t;
            }
        }

        // ---- mid twiddle ----
#pragma unroll
        for (int r = 1; r < 8; ++r) z[r] = cmulh(z[r], M[r]);

        // ---- cross-lane m=32: ONE pswap per complex pair now ----
#pragma unroll
        for (int q = 0; q < 8; q += 2) {
            pswap32h(z[q], z[q + 1]);
            v2h s = z[q] + z[q + 1], d = z[q] - z[q + 1];
            z[q] = s; z[q + 1] = cmulh(d, W32);
        }
        // m=16: pairs (q, q+2)
        {
            const int qs[4] = {0, 1, 4, 5};
#pragma unroll
            for (int t2 = 0; t2 < 4; ++t2) {
                const int q = qs[t2];
                pswap16h(z[q], z[q + 2]);
                v2h s = z[q] + z[q + 2], d = z[q] - z[q + 2];
                z[q] = s; z[q + 2] = cmulh(d, W16);
            }
        }
        // m=8: DPP row_ror:8 == lane xor 8
#pragma unroll
        for (int q = 0; q < 8; ++q) {
            v2h pp = dpph<0x128>(z[q]);
            v2h n  = g8v * z[q] + pp;
            z[q] = cmulh(n, W8);
        }

        // ---- 8x8 transpose through LDS: b32 elements, 65-word rows (2-way free) ----
#pragma unroll
        for (int q = 0; q < 8; ++q) *(v2h*)(wptr + 260 * q) = z[q];
        v2h y[8];
#pragma unroll
        for (int q = 0; q < 8; ++q) y[q] = *(volatile const v2h*)(rptr + 4 * q);

        // ---- register FFT-8 over old lane bits (twiddle-free structure) ----
        {
            v2h d0 = y[0] - y[4]; y[0] += y[4];
            v2h d1 = y[1] - y[5]; y[1] += y[5];
            v2h d2 = y[2] - y[6]; y[2] += y[6];
            v2h d3 = y[3] - y[7]; y[3] += y[7];
            y[4] = d0;
            y[5] = cmulh(d1, W81);
            y[6] = cmulNIh(d2, WNIm);
            y[7] = cmulh(d3, W83);
            v2h t;
            t = y[0] - y[2]; y[0] += y[2]; y[2] = t;
            t = y[1] - y[3]; y[1] += y[3]; y[3] = cmulNIh(t, WNIm);
            t = y[4] - y[6]; y[4] += y[6]; y[6] = t;
            t = y[5] - y[7]; y[5] += y[7]; y[7] = cmulNIh(t, WNIm);
#pragma unroll
            for (int g = 0; g < 8; g += 2) {
                t = y[g] - y[g + 1]; y[g] += y[g + 1]; y[g + 1] = t;
            }
        }

        // ---- energy: v_dot2_f32_f16 into exact f32 accumulators ----
#pragma unroll
        for (int q = 0; q < 8; ++q)
            accQ[q] = __builtin_amdgcn_fdot2(y[q], y[q], accQ[q], false);
    }

    // fold weights once, then wave-reduce
    float acc = 0.0f;
#pragma unroll
    for (int q = 0; q < 8; ++q) acc = fmaf(wt[q], accQ[q], acc);
#pragma unroll
    for (int off = 32; off >= 1; off >>= 1) acc += __shfl_xor(acc, off, 64);
    if (L == 0) ws[waveId] = acc;
}

__global__ void finalize_k(const float* __restrict__ ws, float* __restrict__ out) {
    __shared__ float red[256];
    int t = threadIdx.x;          // 256 threads
    int b = t & 63, g = t >> 6;   // 4 chunks of 32 partials per batch
    float s = 0.0f;
    for (int i = 0; i < 32; ++i) s += ws[b * 128 + g * 32 + i];
    red[t] = s;
    __syncthreads();
    if (t < 64) {
        float band = red[t] + red[t + 64] + red[t + 128] + red[t + 192];
        float lv = 10.0f * log10f(band);
#pragma unroll
        for (int off = 32; off >= 1; off >>= 1) lv += __shfl_xor(lv, off, 64);
        if (t == 0) out[0] = lv * (1.0f / 64.0f);
    }
}

extern "C" void kernel_launch(void* const* d_in, const int* in_sizes, int n_in,
                              void* d_out, int out_size, void* d_ws, size_t ws_size,
                              hipStream_t stream) {
    const float* x = (const float*)d_in[0];
    float* out = (float*)d_out;
    float* ws  = (float*)d_ws;
    fft_band_k<<<(NBATCH * WPB) / 4, 256, 0, stream>>>(x, ws);
    finalize_k<<<1, 256, 0, stream>>>(ws, out);
}

// Round 11
// 106.980 us; speedup vs baseline: 1.0057x; 1.0057x over previous
//
#include <hip/hip_runtime.h>
#include <math.h>

#ifndef M_PI
#define M_PI 3.14159265358979323846
#endif

#define T_LEN   262144
#define NBATCH  64
#define STEP    171
#define NSEG    1531          // (262144-512)/171 + 1
#define NPAIR   766           // ceil(1531/2); last pair has zero imag segment
#define WPB     128           // waves per batch -> 8192 waves total
#define HI_BIN  244           // exclusive upper band bin

typedef float    v2f __attribute__((ext_vector_type(2)));
typedef _Float16 v2h __attribute__((ext_vector_type(2)));   // one complex = 1 VGPR

__device__ __forceinline__ int bitrev3(int r) {
    return ((r & 1) << 2) | (r & 2) | ((r & 4) >> 2);
}

// ---- gfx950 cross-lane helpers (volatile pswap: R6-proven config) ----
__device__ __forceinline__ void pswap32h(v2h& a, v2h& b) {
    asm volatile("v_permlane32_swap_b32 %0, %1" : "+v"(a), "+v"(b));
}
__device__ __forceinline__ void pswap16h(v2h& a, v2h& b) {
    asm volatile("v_permlane16_swap_b32 %0, %1" : "+v"(a), "+v"(b));
}
template <int CTRL>
__device__ __forceinline__ v2h dpph(v2h x) {       // DPP on the packed complex
    int xi = __builtin_bit_cast(int, x);
    int r  = __builtin_amdgcn_mov_dpp(xi, CTRL, 0xF, 0xF, true);
    return __builtin_bit_cast(v2h, r);
}

// complex rotate in f16: z=(x,y), w=(c,s): d = (xc - ys, xs + yc). 2 full-rate VOP3P.
__device__ __forceinline__ v2h cmulh(v2h z, v2h w) {
    v2h t, d;
    asm("v_pk_mul_f16 %0, %1, %2 op_sel_hi:[1,0]"
        : "=v"(t) : "v"(z), "v"(w));
    asm("v_pk_fma_f16 %0, %1, %2, %3 op_sel:[1,1,0] op_sel_hi:[0,1,1] neg_lo:[1,0,0]"
        : "=v"(d) : "v"(z), "v"(w), "v"(t));
    return d;
}
// z * (-i) = (y, -x): single pk_mul with op_sel; m = (1, -1)
__device__ __forceinline__ v2h cmulNIh(v2h z, v2h m) {
    v2h d;
    asm("v_pk_mul_f16 %0, %1, %2 op_sel:[1,0] op_sel_hi:[0,1]"
        : "=v"(d) : "v"(z), "v"(m));
    return d;
}

// volatile pin: opaque def -> cannot be rematerialized or sunk into the loop
#define PINV(x) asm volatile("" : "+v"(x))

// ws layout: [0, 8192) per-wave partial band sums
__global__ __launch_bounds__(256, 6) void fft_band_k(const float* __restrict__ x,
                                                     float* __restrict__ ws) {
    // per-wave transpose scratch: 8 rows x 65 words (260 B) = 2080 B/wave
    __shared__ __align__(16) char ldsc[4 * 2080];

    const int L      = threadIdx.x & 63;
    const int wib    = threadIdx.x >> 6;
    const int waveId = (int)(blockIdx.x * 256 + threadIdx.x) >> 6;
    const int b      = waveId >> 7;           // / WPB
    const int winb   = waveId & (WPB - 1);

    char* wptr = ldsc + wib * 2080 + 4 * L;                            // + 260*q imm
    char* rptr = ldsc + wib * 2080 + 260 * (L & 7) + 4 * (L & 0x38);   // + 4*q imm

    // ---- per-wave loop-invariant constants (volatile-pinned vs remat) ----
    float wv[8];
#pragma unroll
    for (int r = 0; r < 8; ++r) {
        float n = (float)(L + 64 * r);
        wv[r] = 0.54f - 0.46f * __cosf((float)(2.0 * M_PI / 512.0) * n);
        PINV(wv[r]);
    }
    // mid twiddles (c,s) = e^{-2pi i * bitrev3(r) * L / 512}, f16 (RNE via cast)
    v2h M[8];
#pragma unroll
    for (int r = 1; r < 8; ++r) {
        float ang = (float)(-2.0 * M_PI / 512.0) * (float)(bitrev3(r) * L);
        float s, c; __sincosf(ang, &s, &c);
        M[r] = (v2h){(_Float16)c, (_Float16)s};
        PINV(M[r]);
    }
    // cross-lane stage twiddles (m=32,16,8)
    float c32, s32, c16, s16;
    __sincosf((float)(-2.0 * M_PI) * (float)(L & 31) / 64.0f, &s32, &c32);
    __sincosf((float)(-2.0 * M_PI) * (float)(L & 15) / 32.0f, &s16, &c16);
    v2h W32 = (v2h){(_Float16)c32, (_Float16)s32};
    v2h W16 = (v2h){(_Float16)c16, (_Float16)s16};
    v2h W8, g8v;
    if (L & 8) { float s, c; __sincosf((float)(-2.0 * M_PI) * (float)(L & 7) / 16.0f, &s, &c);
                 W8 = (v2h){(_Float16)c, (_Float16)s}; g8v = (v2h){(_Float16)-1.f, (_Float16)-1.f}; }
    else       { W8 = (v2h){(_Float16)1.f, (_Float16)0.f}; g8v = (v2h){(_Float16)1.f, (_Float16)1.f}; }
    PINV(W32); PINV(W16); PINV(W8); PINV(g8v);

    v2h W81  = (v2h){(_Float16)0.70710678f, (_Float16)-0.70710678f};
    v2h W83  = (v2h){(_Float16)-0.70710678f, (_Float16)-0.70710678f};
    v2h WNIm = (v2h){(_Float16)1.f, (_Float16)-1.f};      // for cmulNIh
    PINV(W81); PINV(W83); PINV(WNIm);

    // per-register f32 energy accumulators (weights folded in AFTER the loop)
    float accQ[8];
#pragma unroll
    for (int q = 0; q < 8; ++q) accQ[q] = 0.0f;

    const float* xb = x + (size_t)b * T_LEN;

    for (int p = winb; p < NPAIR; p += WPB) {
        const int s0 = 2 * p;
        v2h z[8];
        const float* p0 = xb + s0 * STEP + L;
        float a[8], bb[8];
#pragma unroll
        for (int r = 0; r < 8; ++r) a[r] = p0[64 * r];
        if (2 * p + 1 < NSEG) {               // wave-uniform; false only at p=765
#pragma unroll
            for (int r = 0; r < 8; ++r) bb[r] = p0[64 * r + STEP];
        } else {
#pragma unroll
            for (int r = 0; r < 8; ++r) bb[r] = 0.0f;
        }
        // f32 window multiply, then pack both segments into one f16 complex reg
#pragma unroll
        for (int r = 0; r < 8; ++r)
            z[r] = (v2h)__builtin_amdgcn_cvt_pkrtz(a[r] * wv[r], bb[r] * wv[r]);

        // ---- per-lane radix-2 DIF FFT-8 over registers (f16 packed complex) ----
        {
            v2h d0 = z[0] - z[4]; z[0] += z[4];
            v2h d1 = z[1] - z[5]; z[1] += z[5];
            v2h d2 = z[2] - z[6]; z[2] += z[6];
            v2h d3 = z[3] - z[7]; z[3] += z[7];
            z[4] = d0;
            z[5] = cmulh(d1, W81);
            z[6] = cmulNIh(d2, WNIm);
            z[7] = cmulh(d3, W83);
            v2h t;
            t = z[0] - z[2]; z[0] += z[2]; z[2] = t;
            t = z[1] - z[3]; z[1] += z[3]; z[3] = cmulNIh(t, WNIm);
            t = z[4] - z[6]; z[4] += z[6]; z[6] = t;
            t = z[5] - z[7]; z[5] += z[7]; z[7] = cmulNIh(t, WNIm);
#pragma unroll
            for (int g = 0; g < 8; g += 2) {
                t = z[g] - z[g + 1]; z[g] += z[g + 1]; z[g + 1] = t;
            }
        }

        // ---- mid twiddle ----
#pragma unroll
        for (int r = 1; r < 8; ++r) z[r] = cmulh(z[r], M[r]);

        // ---- cross-lane m=32: ONE pswap per complex pair ----
#pragma unroll
        for (int q = 0; q < 8; q += 2) {
            pswap32h(z[q], z[q + 1]);
            v2h s = z[q] + z[q + 1], d = z[q] - z[q + 1];
            z[q] = s; z[q + 1] = cmulh(d, W32);
        }
        // m=16: pairs (q, q+2)
        {
            const int qs[4] = {0, 1, 4, 5};
#pragma unroll
            for (int t2 = 0; t2 < 4; ++t2) {
                const int q = qs[t2];
                pswap16h(z[q], z[q + 2]);
                v2h s = z[q] + z[q + 2], d = z[q] - z[q + 2];
                z[q] = s; z[q + 2] = cmulh(d, W16);
            }
        }
        // m=8: DPP row_ror:8 == lane xor 8
#pragma unroll
        for (int q = 0; q < 8; ++q) {
            v2h pp = dpph<0x128>(z[q]);
            v2h n  = g8v * z[q] + pp;
            z[q] = cmulh(n, W8);
        }

        // ---- 8x8 transpose through LDS: b32 elements, 65-word rows (2-way free) ----
#pragma unroll
        for (int q = 0; q < 8; ++q) *(v2h*)(wptr + 260 * q) = z[q];
        v2h y[8];
#pragma unroll
        for (int q = 0; q < 8; ++q) y[q] = *(volatile const v2h*)(rptr + 4 * q);

        // ---- register FFT-8 over old lane bits (twiddle-free structure) ----
        {
            v2h d0 = y[0] - y[4]; y[0] += y[4];
            v2h d1 = y[1] - y[5]; y[1] += y[5];
            v2h d2 = y[2] - y[6]; y[2] += y[6];
            v2h d3 = y[3] - y[7]; y[3] += y[7];
            y[4] = d0;
            y[5] = cmulh(d1, W81);
            y[6] = cmulNIh(d2, WNIm);
            y[7] = cmulh(d3, W83);
            v2h t;
            t = y[0] - y[2]; y[0] += y[2]; y[2] = t;
            t = y[1] - y[3]; y[1] += y[3]; y[3] = cmulNIh(t, WNIm);
            t = y[4] - y[6]; y[4] += y[6]; y[6] = t;
            t = y[5] - y[7]; y[5] += y[7]; y[7] = cmulNIh(t, WNIm);
#pragma unroll
            for (int g = 0; g < 8; g += 2) {
                t = y[g] - y[g + 1]; y[g] += y[g + 1]; y[g + 1] = t;
            }
        }

        // ---- energy: v_dot2_f32_f16 into exact f32 accumulators ----
#pragma unroll
        for (int q = 0; q < 8; ++q)
            accQ[q] = __builtin_amdgcn_fdot2(y[q], y[q], accQ[q], false);
    }

    // ---- weights computed HERE (post-loop): zero VGPR cost inside the loop ----
    // bin at (reg rho, lane L): k = L2 + 2*L4 + 4*L5 + 8*L0 + 16*L1 + 32*L3 + 64*bitrev3(rho)
    float acc = 0.0f;
#pragma unroll
    for (int p = 0; p < 8; ++p) {
        int k = ((L >> 2) & 1) + 2 * ((L >> 4) & 1) + 4 * ((L >> 5) & 1)
              + 8 * (L & 1) + 16 * ((L >> 1) & 1) + 32 * ((L >> 3) & 1)
              + 64 * bitrev3(p);
        int mb = (k <= 256) ? k : 512 - k;
        float wgt = 0.0f;
        if (mb >= 1 && mb < HI_BIN) {
            float f   = (float)mb * (3152.0f / 512.0f);
            float fsq = f * f;
            float num = 1.48693636e8f * fsq * fsq;
            float d1  = fsq + 424.36f;
            float d2  = fsq + 11599.29f;
            float d3  = fsq + 544496.41f;
            float d4  = fsq + 1.48693636e8f;
            float ratio = (num / (d1 * d4)) * rsqrtf(d2 * d3);
            wgt = ratio * ratio * 1.6141422e-9f;   // ratio^2 * 10^0.2 / (winpow*FS*nseg)
        }
        acc = fmaf(wgt, accQ[p], acc);
    }
    // wave reduction -> one uncontended store per wave
#pragma unroll
    for (int off = 32; off >= 1; off >>= 1) acc += __shfl_xor(acc, off, 64);
    if (L == 0) ws[waveId] = acc;
}

__global__ void finalize_k(const float* __restrict__ ws, float* __restrict__ out) {
    __shared__ float red[256];
    int t = threadIdx.x;          // 256 threads
    int b = t & 63, g = t >> 6;   // 4 chunks of 32 partials per batch
    float s = 0.0f;
    for (int i = 0; i < 32; ++i) s += ws[b * 128 + g * 32 + i];
    red[t] = s;
    __syncthreads();
    if (t < 64) {
        float band = red[t] + red[t + 64] + red[t + 128] + red[t + 192];
        float lv = 10.0f * log10f(band);
#pragma unroll
        for (int off = 32; off >= 1; off >>= 1) lv += __shfl_xor(lv, off, 64);
        if (t == 0) out[0] = lv * (1.0f / 64.0f);
    }
}

extern "C" void kernel_launch(void* const* d_in, const int* in_sizes, int n_in,
                              void* d_out, int out_size, void* d_ws, size_t ws_size,
                              hipStream_t stream) {
    const float* x = (const float*)d_in[0];
    float* out = (float*)d_out;
    float* ws  = (float*)d_ws;
    fft_band_k<<<(NBATCH * WPB) / 4, 256, 0, stream>>>(x, ws);
    finalize_k<<<1, 256, 0, stream>>>(ws, out);
}